// Round 8
// baseline (320.906 us; speedup 1.0000x reference)
//
#include <hip/hip_runtime.h>
#include <hip/hip_bf16.h>

// GCN: 2x GCNConv(+self-loops, sym-norm) + ReLU, then Linear(64->1).
// N=100000 nodes, E=1600000 edges, IN=128, HID=64, OUT=1.
//
//  - R7 fix: agg was latency-chain-bound (col load -> readfirstlane ->
//    gather serialized; 55.8us @ 32% VALU, no BW ceiling hit). Now the
//    wave preloads all <=64 row indices in ONE coalesced load and
//    distributes via __shfl (bpermute) -> gathers issue back-to-back,
//    16 edges unrolled (8 in flight per half-wave).
//  - gemm_tile: register-double-buffered staging (prefetch chunk k+1
//    during compute of chunk k) to overlap HBM latency with FMAs.
//  - Ts stored bf16 (packed bf16x2): 128B/edge gather, fp32 accumulate.
//  - Exact two-level counting-sort CSR build (R5/R6).
//  - norm factored into GEMM epilogue: out[d]=dq_d*(Ts[d]+sum Ts[s]).

#define IN_DIM 128
#define HID 64
#define B1 256        // level-1 blocks (chunks)
#define MAXNC 128     // max coarse buckets (N <= 131072)

typedef unsigned int uint;

__device__ inline uint pack_bf16x2(float a, float b) {
    uint ua = __builtin_bit_cast(uint, a);
    uint ub = __builtin_bit_cast(uint, b);
    ua += 0x7fffu + ((ua >> 16) & 1u);   // RNE
    ub += 0x7fffu + ((ub >> 16) & 1u);
    return (ua >> 16) | (ub & 0xffff0000u);
}
__device__ inline float bf_lo(uint g) { return __builtin_bit_cast(float, g << 16); }
__device__ inline float bf_hi(uint g) { return __builtin_bit_cast(float, g & 0xffff0000u); }

// ---------------- level-1 histogram: coarse buckets (dst>>10) per chunk ----------------
__global__ __launch_bounds__(512) void hist1(const int* __restrict__ dst,
                                             int* __restrict__ ghist,
                                             int E, int NC, int chunk) {
    __shared__ int h[MAXNC];
    int t = threadIdx.x, blk = blockIdx.x;
    if (t < NC) h[t] = 0;
    __syncthreads();
    int s = blk * chunk, e = min(E, s + chunk);
    for (int i = s + t; i < e; i += 512) atomicAdd(&h[dst[i] >> 10], 1);
    __syncthreads();
    if (t < NC) ghist[(size_t)t * B1 + blk] = h[t];
}

// ---------------- exclusive scan of ghist (NC*B1 elems, in place) ----------------
__global__ __launch_bounds__(1024) void scan_mat(int* __restrict__ a, int M,
                                                 int* __restrict__ row_off, int N) {
    __shared__ int ws[16], wsoff[16], total_s;
    int t = threadIdx.x;
    int seg = (M + 1023) >> 10;
    int s = t * seg, e = min(M, s + seg);
    int sum = 0;
    for (int i = s; i < e; ++i) sum += a[i];
    int incl = sum;
#pragma unroll
    for (int o = 1; o < 64; o <<= 1) {
        int u = __shfl_up(incl, o, 64);
        if ((t & 63) >= o) incl += u;
    }
    if ((t & 63) == 63) ws[t >> 6] = incl;
    __syncthreads();
    if (t == 0) {
        int run = 0;
#pragma unroll
        for (int i = 0; i < 16; ++i) { wsoff[i] = run; run += ws[i]; }
        total_s = run;
    }
    __syncthreads();
    int run = wsoff[t >> 6] + incl - sum;  // exclusive prefix at segment start
    for (int i = s; i < e; ++i) { int tmp = a[i]; a[i] = run; run += tmp; }
    if (t == 0) row_off[N] = total_s;  // == E
}

// ---------------- level-1 scatter: sequential runs per (block,bucket) ----------------
__global__ __launch_bounds__(512) void scatter1(const int* __restrict__ src,
                                                const int* __restrict__ dst,
                                                const int* __restrict__ goff,
                                                int2* __restrict__ pairs,
                                                int E, int NC, int chunk) {
    __shared__ int cur[MAXNC];
    int t = threadIdx.x, blk = blockIdx.x;
    if (t < NC) cur[t] = goff[(size_t)t * B1 + blk];
    __syncthreads();
    int s = blk * chunk, e = min(E, s + chunk);
    for (int i = s + t; i < e; i += 512) {
        int d = dst[i];
        int p = atomicAdd(&cur[d >> 10], 1);  // LDS cursor holds global pos
        pairs[p] = make_int2(src[i], d);
    }
}

// ---------------- level-2: per-bucket CSR build (exact) ----------------
__global__ __launch_bounds__(1024) void build_csr(const int2* __restrict__ pairs,
                                                  const int* __restrict__ goff,
                                                  int* __restrict__ row_off,
                                                  float* __restrict__ disqrt,
                                                  int* __restrict__ col,
                                                  int E, int NC, int N) {
    __shared__ int h[1024], cur[1024];
    __shared__ int ws[16], wsoff[16];
    int b = blockIdx.x, t = threadIdx.x;
    int base = goff[(size_t)b * B1];
    int next = (b + 1 < NC) ? goff[(size_t)(b + 1) * B1] : E;
    h[t] = 0;
    __syncthreads();
    for (int i = base + t; i < next; i += 1024)
        atomicAdd(&h[pairs[i].y & 1023], 1);
    __syncthreads();
    int deg = h[t];
    int incl = deg;
#pragma unroll
    for (int o = 1; o < 64; o <<= 1) {
        int u = __shfl_up(incl, o, 64);
        if ((t & 63) >= o) incl += u;
    }
    if ((t & 63) == 63) ws[t >> 6] = incl;
    __syncthreads();
    if (t == 0) {
        int run = 0;
#pragma unroll
        for (int i = 0; i < 16; ++i) { wsoff[i] = run; run += ws[i]; }
    }
    __syncthreads();
    int excl = wsoff[t >> 6] + incl - deg;
    cur[t] = base + excl;
    int node = (b << 10) + t;
    if (node < N) {
        row_off[node] = base + excl;
        disqrt[node]  = rsqrtf((float)(deg + 1));  // +1 self-loop
    }
    __syncthreads();
    for (int i = base + t; i < next; i += 1024) {
        int2 p = pairs[i];
        int pos = atomicAdd(&cur[p.y & 1023], 1);  // LDS atomic, global pos
        col[pos] = p.x;                            // 65KB window, single XCD
    }
}

// ---------------- tiled GEMM (pipelined): Ts_bf16 = (X @ W) * disqrt ----------------
template <int K>
__global__ __launch_bounds__(256) void gemm_tile(const float* __restrict__ X,
                                                 const float* __restrict__ W,
                                                 const float* __restrict__ disqrt,
                                                 uint* __restrict__ Tsb, int n) {
    __shared__ float xs[32][68];   // [k][m]; stride 68 keeps rows 16B-aligned
    __shared__ float ws[32][64];   // [k][c]
    const int tid  = threadIdx.x;
    const int nIdx = tid & 15;     // cols 4*nIdx..+3
    const int mIdx = tid >> 4;     // nodes 4*mIdx..+3
    const int m0   = blockIdx.x * 64;
    const int r0 = tid >> 3, kq = tid & 7, r1 = r0 + 32;
    const int wk = tid >> 4, wc = tid & 15;
    const int row0 = m0 + r0, row1 = m0 + r1;
    const float4 z4 = make_float4(0.f, 0.f, 0.f, 0.f);

    // prologue: load chunk 0 into registers
    float4 gx0 = (row0 < n) ? *(const float4*)(X + (size_t)row0 * K + 4 * kq) : z4;
    float4 gx1 = (row1 < n) ? *(const float4*)(X + (size_t)row1 * K + 4 * kq) : z4;
    float4 gw0 = *(const float4*)(W + (size_t)wk * 64 + 4 * wc);
    float4 gw1 = *(const float4*)(W + (size_t)(wk + 16) * 64 + 4 * wc);

    float acc[4][4] = {};
    for (int kc = 0;;) {
        // write staged registers to LDS (x transposed)
        xs[4 * kq + 0][r0] = gx0.x; xs[4 * kq + 1][r0] = gx0.y;
        xs[4 * kq + 2][r0] = gx0.z; xs[4 * kq + 3][r0] = gx0.w;
        xs[4 * kq + 0][r1] = gx1.x; xs[4 * kq + 1][r1] = gx1.y;
        xs[4 * kq + 2][r1] = gx1.z; xs[4 * kq + 3][r1] = gx1.w;
        *(float4*)&ws[wk][4 * wc]      = gw0;
        *(float4*)&ws[wk + 16][4 * wc] = gw1;
        __syncthreads();
        kc += 32;
        const bool more = kc < K;
        if (more) {  // prefetch next chunk; latency overlaps compute below
            gx0 = (row0 < n) ? *(const float4*)(X + (size_t)row0 * K + kc + 4 * kq) : z4;
            gx1 = (row1 < n) ? *(const float4*)(X + (size_t)row1 * K + kc + 4 * kq) : z4;
            gw0 = *(const float4*)(W + (size_t)(kc + wk) * 64 + 4 * wc);
            gw1 = *(const float4*)(W + (size_t)(kc + wk + 16) * 64 + 4 * wc);
        }
#pragma unroll 8
        for (int k = 0; k < 32; ++k) {
            float4 a = *(const float4*)&xs[k][4 * mIdx];
            float4 b = *(const float4*)&ws[k][4 * nIdx];
            const float* ap = (const float*)&a;
            const float* bp = (const float*)&b;
#pragma unroll
            for (int mi = 0; mi < 4; ++mi)
#pragma unroll
                for (int ni = 0; ni < 4; ++ni)
                    acc[mi][ni] += ap[mi] * bp[ni];
        }
        if (!more) break;
        __syncthreads();
    }
#pragma unroll
    for (int mi = 0; mi < 4; ++mi) {
        int row = m0 + 4 * mIdx + mi;
        if (row < n) {
            float s = disqrt[row];
            uint2 pk;
            pk.x = pack_bf16x2(acc[mi][0] * s, acc[mi][1] * s);
            pk.y = pack_bf16x2(acc[mi][2] * s, acc[mi][3] * s);
            *(uint2*)(Tsb + (size_t)row * 32 + 2 * nIdx) = pk;
        }
    }
}

// ---------------- aggregation: wave per node, indices preloaded + shfl ----------------
// out[d] = relu(disqrt[d] * (Ts[d] + sum_e Ts[col[e]]) + bias)
// Tsb: packed bf16x2, 32 uints per node row (128B). Half-wave per edge.
template <bool FUSE_FC>
__global__ __launch_bounds__(256) void agg_kernel(const uint* __restrict__ Tsb,
                                                  const int* __restrict__ row_off,
                                                  const int* __restrict__ col,
                                                  const float* __restrict__ disqrt,
                                                  const float* __restrict__ bias,
                                                  const float* __restrict__ wfc,
                                                  const float* __restrict__ bfc,
                                                  float* __restrict__ out, int n) {
    int node = blockIdx.x * 4 + (threadIdx.x >> 6);
    if (node >= n) return;
    int lane = threadIdx.x & 63;
    int h = lane >> 5;      // half-wave id: which edge of a pair
    int p = lane & 31;      // feature pair index (features 2p, 2p+1)
    float2 acc = make_float2(0.f, 0.f);
    {   // self-loop (half 0 only)
        uint g = Tsb[(size_t)node * 32 + p];
        if (h == 0) { acc.x = bf_lo(g); acc.y = bf_hi(g); }
    }
    int beg = __builtin_amdgcn_readfirstlane(row_off[node]);
    int end = __builtin_amdgcn_readfirstlane(row_off[node + 1]);
    for (int batch = beg; batch < end; batch += 64) {
        int bn = min(64, end - batch);
        int cv = 0;
        if (batch + lane < end) cv = col[batch + lane];  // ONE coalesced load
        int j = 0;
        for (; j + 16 <= bn; j += 16) {   // 16 edges: 8 gathers in flight per half
            int s0 = __shfl(cv, j + 0 + h, 64);
            int s1 = __shfl(cv, j + 2 + h, 64);
            int s2 = __shfl(cv, j + 4 + h, 64);
            int s3 = __shfl(cv, j + 6 + h, 64);
            int s4 = __shfl(cv, j + 8 + h, 64);
            int s5 = __shfl(cv, j + 10 + h, 64);
            int s6 = __shfl(cv, j + 12 + h, 64);
            int s7 = __shfl(cv, j + 14 + h, 64);
            uint g0 = Tsb[(size_t)s0 * 32 + p];
            uint g1 = Tsb[(size_t)s1 * 32 + p];
            uint g2 = Tsb[(size_t)s2 * 32 + p];
            uint g3 = Tsb[(size_t)s3 * 32 + p];
            uint g4 = Tsb[(size_t)s4 * 32 + p];
            uint g5 = Tsb[(size_t)s5 * 32 + p];
            uint g6 = Tsb[(size_t)s6 * 32 + p];
            uint g7 = Tsb[(size_t)s7 * 32 + p];
            acc.x += bf_lo(g0); acc.y += bf_hi(g0);
            acc.x += bf_lo(g1); acc.y += bf_hi(g1);
            acc.x += bf_lo(g2); acc.y += bf_hi(g2);
            acc.x += bf_lo(g3); acc.y += bf_hi(g3);
            acc.x += bf_lo(g4); acc.y += bf_hi(g4);
            acc.x += bf_lo(g5); acc.y += bf_hi(g5);
            acc.x += bf_lo(g6); acc.y += bf_hi(g6);
            acc.x += bf_lo(g7); acc.y += bf_hi(g7);
        }
        for (; j + 2 <= bn; j += 2) {
            int s = __shfl(cv, j + h, 64);
            uint g = Tsb[(size_t)s * 32 + p];
            acc.x += bf_lo(g); acc.y += bf_hi(g);
        }
        if (j < bn) {                     // odd leftover: half 0 only
            int s = __shfl(cv, j, 64);
            uint g = Tsb[(size_t)s * 32 + p];
            if (h == 0) { acc.x += bf_lo(g); acc.y += bf_hi(g); }
        }
    }
    // combine halves
    acc.x += __shfl_xor(acc.x, 32, 64);
    acc.y += __shfl_xor(acc.y, 32, 64);
    float dq = disqrt[node];
    float2 bv = *(const float2*)(bias + 2 * p);
    float rx = fmaxf(acc.x * dq + bv.x, 0.f);
    float ry = fmaxf(acc.y * dq + bv.y, 0.f);
    if (!FUSE_FC) {
        if (h == 0)
            *(float2*)(out + (size_t)node * HID + 2 * p) = make_float2(rx, ry);
    } else {
        float2 wv = *(const float2*)(wfc + 2 * p);
        float v = rx * wv.x + ry * wv.y;
        v += __shfl_down(v, 16, 64);
        v += __shfl_down(v, 8, 64);
        v += __shfl_down(v, 4, 64);
        v += __shfl_down(v, 2, 64);
        v += __shfl_down(v, 1, 64);
        if (lane == 0) out[node] = v + bfc[0];
    }
}

extern "C" void kernel_launch(void* const* d_in, const int* in_sizes, int n_in,
                              void* d_out, int out_size, void* d_ws, size_t ws_size,
                              hipStream_t stream) {
    const float* x   = (const float*)d_in[0];
    const int*   ei  = (const int*)d_in[1];
    const float* W1  = (const float*)d_in[2];
    const float* b1  = (const float*)d_in[3];
    const float* W2  = (const float*)d_in[4];
    const float* b2  = (const float*)d_in[5];
    const float* Wfc = (const float*)d_in[6];
    const float* bfc = (const float*)d_in[7];
    float* out = (float*)d_out;

    const int N = in_sizes[0] / IN_DIM;
    const int E = in_sizes[1] / 2;
    const int* src = ei;
    const int* dst = ei + E;
    const int NC    = (N + 1023) >> 10;      // coarse buckets (1024 nodes each)
    const int chunk = (E + B1 - 1) / B1;     // edges per level-1 block

    // ---- workspace carve-up (256B aligned) ----
    char* w = (char*)d_ws;
    auto alloc = [&](size_t bytes) {
        void* p = (void*)w;
        w += (bytes + 255) & ~(size_t)255;
        return p;
    };
    int*   row_off = (int*)alloc((size_t)(N + 1) * 4);
    float* disqrt  = (float*)alloc((size_t)N * 4);
    int*   goff    = (int*)alloc((size_t)NC * B1 * 4);
    int*   col     = (int*)alloc((size_t)E * 4);
    // scratch region reused: pairs (E*8) first, then Ts bf16 (N*128B)
    size_t scrA = (size_t)E * 8, scrB = (size_t)N * HID * 2;
    void*  scr  = alloc(scrA > scrB ? scrA : scrB);
    float* h1   = (float*)alloc((size_t)N * HID * 4);
    int2*  pairs = (int2*)scr;
    uint*  Tsb   = (uint*)scr;

    // ---- build CSR (exact two-level counting sort) ----
    hist1<<<B1, 512, 0, stream>>>(dst, goff, E, NC, chunk);
    scan_mat<<<1, 1024, 0, stream>>>(goff, NC * B1, row_off, N);
    scatter1<<<B1, 512, 0, stream>>>(src, dst, goff, pairs, E, NC, chunk);
    build_csr<<<NC, 1024, 0, stream>>>(pairs, goff, row_off, disqrt, col, E, NC, N);

    // ---- layer 1 ----
    gemm_tile<IN_DIM><<<(N + 63) / 64, 256, 0, stream>>>(x, W1, disqrt, Tsb, N);
    agg_kernel<false><<<(N + 3) / 4, 256, 0, stream>>>(Tsb, row_off, col, disqrt,
                                                       b1, nullptr, nullptr, h1, N);

    // ---- layer 2 + fused fc ----
    gemm_tile<HID><<<(N + 63) / 64, 256, 0, stream>>>(h1, W2, disqrt, Tsb, N);
    agg_kernel<true><<<(N + 3) / 4, 256, 0, stream>>>(Tsb, row_off, col, disqrt,
                                                      b2, Wfc, bfc, out, N);
}